// Round 1
// baseline (83.746 us; speedup 1.0000x reference)
//
#include <hip/hip_runtime.h>
#include <math.h>

#define NQ 9
#define NL 5
#define NC 10

__device__ __forceinline__ float shx(float v, int m) { return __shfl_xor(v, m, 64); }

// ---- single-qubit RX on a lane bit (symmetric matrix: new = c*mine + (-i s)*other) ----
template<int LB>
__device__ __forceinline__ void rx_cross(float (&sr)[8], float (&si)[8], float c, float s) {
#pragma unroll
    for (int k = 0; k < 8; ++k) {
        float pr = shx(sr[k], 1 << LB);
        float pi = shx(si[k], 1 << LB);
        float ar = sr[k], ai = si[k];
        sr[k] = c * ar + s * pi;
        si[k] = c * ai - s * pr;
    }
}

// ---- single-qubit RX on a local (in-register) bit ----
template<int B>
__device__ __forceinline__ void rx_local(float (&sr)[8], float (&si)[8], float c, float s) {
#pragma unroll
    for (int k = 0; k < 8; ++k) {
        if ((k >> B) & 1) continue;
        const int k1 = k | (1 << B);
        float a0r = sr[k], a0i = si[k], a1r = sr[k1], a1i = si[k1];
        sr[k]  = c * a0r + s * a1i;
        si[k]  = c * a0i - s * a1r;
        sr[k1] = c * a1r + s * a0i;
        si[k1] = c * a1i - s * a0r;
    }
}

// ---- general 2x2 complex gate (Rot) on a lane bit ----
// m = {m00r,m00i, m01r,m01i, m10r,m10i, m11r,m11i}
template<int LB>
__device__ __forceinline__ void rot_cross(float (&sr)[8], float (&si)[8],
                                          const float* __restrict__ m, int lane) {
    const int bit = (lane >> LB) & 1;
    float msr = bit ? m[6] : m[0];
    float msi = bit ? m[7] : m[1];
    float mor = bit ? m[4] : m[2];
    float moi = bit ? m[5] : m[3];
#pragma unroll
    for (int k = 0; k < 8; ++k) {
        float pr = shx(sr[k], 1 << LB);
        float pi = shx(si[k], 1 << LB);
        float ar = sr[k], ai = si[k];
        sr[k] = msr * ar - msi * ai + mor * pr - moi * pi;
        si[k] = msr * ai + msi * ar + mor * pi + moi * pr;
    }
}

// ---- general 2x2 complex gate (Rot) on a local bit ----
template<int B>
__device__ __forceinline__ void rot_local(float (&sr)[8], float (&si)[8],
                                          const float* __restrict__ m) {
    float m00r = m[0], m00i = m[1], m01r = m[2], m01i = m[3];
    float m10r = m[4], m10i = m[5], m11r = m[6], m11i = m[7];
#pragma unroll
    for (int k = 0; k < 8; ++k) {
        if ((k >> B) & 1) continue;
        const int k1 = k | (1 << B);
        float a0r = sr[k], a0i = si[k], a1r = sr[k1], a1i = si[k1];
        sr[k]  = m00r*a0r - m00i*a0i + m01r*a1r - m01i*a1i;
        si[k]  = m00r*a0i + m00i*a0r + m01r*a1i + m01i*a1r;
        sr[k1] = m10r*a0r - m10i*a0i + m11r*a1r - m11i*a1i;
        si[k1] = m10r*a0i + m10i*a0r + m11r*a1i + m11i*a1r;
    }
}

// ---- CRX: ctrl lane bit CB, tgt lane bit TB ----
template<int CB, int TB>
__device__ __forceinline__ void crx_ll(float (&sr)[8], float (&si)[8], float c, float s, int lane) {
    const bool ctrl = (lane >> CB) & 1;
#pragma unroll
    for (int k = 0; k < 8; ++k) {
        float pr = shx(sr[k], 1 << TB);
        float pi = shx(si[k], 1 << TB);
        float nr = c * sr[k] + s * pi;
        float ni = c * si[k] - s * pr;
        sr[k] = ctrl ? nr : sr[k];
        si[k] = ctrl ? ni : si[k];
    }
}

// ---- CRX: ctrl lane bit CB, tgt local bit TB ----
template<int CB, int TB>
__device__ __forceinline__ void crx_lt(float (&sr)[8], float (&si)[8], float c, float s, int lane) {
    const bool ctrl = (lane >> CB) & 1;
#pragma unroll
    for (int k = 0; k < 8; ++k) {
        if ((k >> TB) & 1) continue;
        const int k1 = k | (1 << TB);
        float a0r = sr[k], a0i = si[k], a1r = sr[k1], a1i = si[k1];
        float n0r = c * a0r + s * a1i;
        float n0i = c * a0i - s * a1r;
        float n1r = c * a1r + s * a0i;
        float n1i = c * a1i - s * a0r;
        sr[k]  = ctrl ? n0r : a0r;  si[k]  = ctrl ? n0i : a0i;
        sr[k1] = ctrl ? n1r : a1r;  si[k1] = ctrl ? n1i : a1i;
    }
}

// ---- CRX: ctrl local bit CB, tgt local bit TB ----
template<int CB, int TB>
__device__ __forceinline__ void crx_tt(float (&sr)[8], float (&si)[8], float c, float s) {
#pragma unroll
    for (int k = 0; k < 8; ++k) {
        if (!((k >> CB) & 1)) continue;
        if ((k >> TB) & 1) continue;
        const int k1 = k | (1 << TB);
        float a0r = sr[k], a0i = si[k], a1r = sr[k1], a1i = si[k1];
        sr[k]  = c * a0r + s * a1i;
        si[k]  = c * a0i - s * a1r;
        sr[k1] = c * a1r + s * a0i;
        si[k1] = c * a1i - s * a0r;
    }
}

// ---- CRX: ctrl local bit CB, tgt lane bit TB ----
template<int CB, int TB>
__device__ __forceinline__ void crx_tl(float (&sr)[8], float (&si)[8], float c, float s) {
#pragma unroll
    for (int k = 0; k < 8; ++k) {
        if (!((k >> CB) & 1)) continue;
        float pr = shx(sr[k], 1 << TB);
        float pi = shx(si[k], 1 << TB);
        sr[k] = c * sr[k] + s * pi;
        si[k] = c * si[k] - s * pr;
    }
}

__global__ __launch_bounds__(256) void qmlp_kernel(
    const float* __restrict__ x, const float* __restrict__ rot_w,
    const float* __restrict__ crx_w, const float* __restrict__ fc_w,
    const float* __restrict__ fc_b, float* __restrict__ out, int B)
{
    __shared__ float rotm[NL * NQ * 8];
    __shared__ float crxm[NL * NQ * 2];
    __shared__ float fcw[NC * NQ];
    __shared__ float fcbs[NC];

    const int tid = threadIdx.x;
    if (tid < NL * NQ) {
        const float phi = rot_w[tid * 3 + 0];
        const float th  = rot_w[tid * 3 + 1];
        const float om  = rot_w[tid * 3 + 2];
        float st, ct; sincosf(0.5f * th, &st, &ct);
        float spo, cpo; sincosf(0.5f * (phi + om), &spo, &cpo);
        float smo, cmo; sincosf(0.5f * (phi - om), &smo, &cmo);
        float* m = rotm + tid * 8;
        // PennyLane Rot = RZ(om) RY(th) RZ(phi)
        m[0] =  ct * cpo; m[1] = -ct * spo;   // m00 = e^{-i(phi+om)/2} ct
        m[2] = -st * cmo; m[3] = -st * smo;   // m01 = -e^{+i(phi-om)/2} st
        m[4] =  st * cmo; m[5] = -st * smo;   // m10 =  e^{-i(phi-om)/2} st
        m[6] =  ct * cpo; m[7] =  ct * spo;   // m11 = e^{+i(phi+om)/2} ct
        float sc, cc; sincosf(0.5f * crx_w[tid], &sc, &cc);
        crxm[tid * 2 + 0] = cc; crxm[tid * 2 + 1] = sc;
    }
    if (tid < NC * NQ) fcw[tid] = fc_w[tid];
    if (tid < NC) fcbs[tid] = fc_b[tid];
    __syncthreads();

    const int lane = tid & 63;
    const int b = blockIdx.x * 4 + (tid >> 6);
    if (b >= B) return;

    // per-sample RX angles (same x re-embedded every layer)
    float cx[NQ], sx[NQ];
#pragma unroll
    for (int w = 0; w < NQ; ++w) sincosf(0.5f * x[b * NQ + w], &sx[w], &cx[w]);

    // state: lane owns amplitudes idx = lane*8 + k. bit(wire w) = 8-w;
    // wires 0..5 -> lane bits 5..0, wires 6..8 -> local bits 2..0.
    float sr[8], si[8];
#pragma unroll
    for (int k = 0; k < 8; ++k) { sr[k] = 0.f; si[k] = 0.f; }
    if (lane == 0) sr[0] = 1.f;

    for (int n = 0; n < NL; ++n) {
        // AngleEmbedding RX(x_w)
        rx_cross<5>(sr, si, cx[0], sx[0]);
        rx_cross<4>(sr, si, cx[1], sx[1]);
        rx_cross<3>(sr, si, cx[2], sx[2]);
        rx_cross<2>(sr, si, cx[3], sx[3]);
        rx_cross<1>(sr, si, cx[4], sx[4]);
        rx_cross<0>(sr, si, cx[5], sx[5]);
        rx_local<2>(sr, si, cx[6], sx[6]);
        rx_local<1>(sr, si, cx[7], sx[7]);
        rx_local<0>(sr, si, cx[8], sx[8]);
        // Rot
        const float* M = rotm + n * NQ * 8;
        rot_cross<5>(sr, si, M + 0 * 8, lane);
        rot_cross<4>(sr, si, M + 1 * 8, lane);
        rot_cross<3>(sr, si, M + 2 * 8, lane);
        rot_cross<2>(sr, si, M + 3 * 8, lane);
        rot_cross<1>(sr, si, M + 4 * 8, lane);
        rot_cross<0>(sr, si, M + 5 * 8, lane);
        rot_local<2>(sr, si, M + 6 * 8);
        rot_local<1>(sr, si, M + 7 * 8);
        rot_local<0>(sr, si, M + 8 * 8);
        // CRX ring: ctrl w (bit 8-w), tgt (w+1)%9
        const float* C = crxm + n * NQ * 2;
        crx_ll<5, 4>(sr, si, C[0],  C[1],  lane);  // w=0
        crx_ll<4, 3>(sr, si, C[2],  C[3],  lane);  // w=1
        crx_ll<3, 2>(sr, si, C[4],  C[5],  lane);  // w=2
        crx_ll<2, 1>(sr, si, C[6],  C[7],  lane);  // w=3
        crx_ll<1, 0>(sr, si, C[8],  C[9],  lane);  // w=4
        crx_lt<0, 2>(sr, si, C[10], C[11], lane);  // w=5
        crx_tt<2, 1>(sr, si, C[12], C[13]);        // w=6
        crx_tt<1, 0>(sr, si, C[14], C[15]);        // w=7
        crx_tl<0, 5>(sr, si, C[16], C[17]);        // w=8
    }

    // probabilities and <Z_w>
    float p[8];
#pragma unroll
    for (int k = 0; k < 8; ++k) p[k] = sr[k] * sr[k] + si[k] * si[k];
    float psum = 0.f;
#pragma unroll
    for (int k = 0; k < 8; ++k) psum += p[k];

    float ev[NQ];
#pragma unroll
    for (int w = 0; w < 6; ++w) ev[w] = ((lane >> (5 - w)) & 1) ? -psum : psum;
    ev[6] = (p[0] + p[1] + p[2] + p[3]) - (p[4] + p[5] + p[6] + p[7]);
    ev[7] = (p[0] + p[1] + p[4] + p[5]) - (p[2] + p[3] + p[6] + p[7]);
    ev[8] = (p[0] + p[2] + p[4] + p[6]) - (p[1] + p[3] + p[5] + p[7]);

#pragma unroll
    for (int m = 1; m < 64; m <<= 1) {
#pragma unroll
        for (int w = 0; w < NQ; ++w) ev[w] += shx(ev[w], m);
    }

    // linear head + log_softmax: lane c (<10) owns class c
    float lval = -INFINITY;
    if (lane < NC) {
        float d = fcbs[lane];
        const float* fw = fcw + lane * NQ;
#pragma unroll
        for (int w = 0; w < NQ; ++w) d += ev[w] * fw[w];
        lval = d;
    }
    float mx = lval;
    mx = fmaxf(mx, shx(mx, 1));
    mx = fmaxf(mx, shx(mx, 2));
    mx = fmaxf(mx, shx(mx, 4));
    mx = fmaxf(mx, shx(mx, 8));
    float e = (lane < NC) ? expf(lval - mx) : 0.f;
    float se = e;
    se += shx(se, 1); se += shx(se, 2); se += shx(se, 4); se += shx(se, 8);
    if (lane < NC) out[b * NC + lane] = lval - mx - logf(se);
}

extern "C" void kernel_launch(void* const* d_in, const int* in_sizes, int n_in,
                              void* d_out, int out_size, void* d_ws, size_t ws_size,
                              hipStream_t stream) {
    const float* x     = (const float*)d_in[0];
    const float* rot_w = (const float*)d_in[1];
    const float* crx_w = (const float*)d_in[2];
    const float* fc_w  = (const float*)d_in[3];
    const float* fc_b  = (const float*)d_in[4];
    float* out = (float*)d_out;
    const int B = in_sizes[0] / NQ;          // 4096
    const int blocks = (B + 3) / 4;          // 4 samples (waves) per 256-thread block
    qmlp_kernel<<<blocks, 256, 0, stream>>>(x, rot_w, crx_w, fc_w, fc_b, out, B);
}

// Round 2
// 65.350 us; speedup vs baseline: 1.2815x; 1.2815x over previous
//
#include <hip/hip_runtime.h>
#include <math.h>

#define NQ 9
#define NL 5
#define NC 10

__device__ __forceinline__ float shx(float v, int m) { return __shfl_xor(v, m, 64); }

// ---- fused (Rot*RX) general 2x2 on a lane bit ----
// m = {m00r,m00i, m01r,m01i, m10r,m10i, m11r,m11i} (Rot matrix), c=cos(x/2), s=sin(x/2)
// U = M_rot * RX(x);  lane applies row `bit`: new = diag*mine + off*partner
template<int LB>
__device__ __forceinline__ void fused_cross(float (&sr)[8], float (&si)[8],
                                            const float* __restrict__ m,
                                            float c, float s, int lane) {
    const int bit = (lane >> LB) & 1;
    float mAr = bit ? m[6] : m[0];   // diag rot element
    float mAi = bit ? m[7] : m[1];
    float mBr = bit ? m[4] : m[2];   // off-diag rot element
    float mBi = bit ? m[5] : m[3];
    // diag = mA*c + mB*(-i s); off = mB*c + mA*(-i s)
    float dr = mAr * c + s * mBi;
    float di = mAi * c - s * mBr;
    float er = mBr * c + s * mAi;
    float ei = mBi * c - s * mAr;
#pragma unroll
    for (int k = 0; k < 8; ++k) {
        float pr = shx(sr[k], 1 << LB);
        float pi = shx(si[k], 1 << LB);
        float ar = sr[k], ai = si[k];
        sr[k] = dr * ar - di * ai + er * pr - ei * pi;
        si[k] = dr * ai + di * ar + er * pi + ei * pr;
    }
}

// ---- fused (Rot*RX) general 2x2 on a local bit ----
template<int B>
__device__ __forceinline__ void fused_local(float (&sr)[8], float (&si)[8],
                                            const float* __restrict__ m,
                                            float c, float s) {
    float u00r = m[0]*c + s*m[3], u00i = m[1]*c - s*m[2];
    float u01r = m[2]*c + s*m[1], u01i = m[3]*c - s*m[0];
    float u10r = m[4]*c + s*m[7], u10i = m[5]*c - s*m[6];
    float u11r = m[6]*c + s*m[5], u11i = m[7]*c - s*m[4];
#pragma unroll
    for (int k = 0; k < 8; ++k) {
        if ((k >> B) & 1) continue;
        const int k1 = k | (1 << B);
        float a0r = sr[k], a0i = si[k], a1r = sr[k1], a1i = si[k1];
        sr[k]  = u00r*a0r - u00i*a0i + u01r*a1r - u01i*a1i;
        si[k]  = u00r*a0i + u00i*a0r + u01r*a1i + u01i*a1r;
        sr[k1] = u10r*a0r - u10i*a0i + u11r*a1r - u11i*a1i;
        si[k1] = u10r*a0i + u10i*a0r + u11r*a1i + u11i*a1r;
    }
}

// ---- CRX variants (control folded into coefficients where ctrl is a lane bit) ----
template<int CB, int TB>
__device__ __forceinline__ void crx_ll(float (&sr)[8], float (&si)[8], float c, float s, int lane) {
    const bool ctrl = (lane >> CB) & 1;
    const float ce = ctrl ? c : 1.f;
    const float se = ctrl ? s : 0.f;
#pragma unroll
    for (int k = 0; k < 8; ++k) {
        float pr = shx(sr[k], 1 << TB);
        float pi = shx(si[k], 1 << TB);
        sr[k] = ce * sr[k] + se * pi;
        si[k] = ce * si[k] - se * pr;
    }
}

template<int CB, int TB>
__device__ __forceinline__ void crx_lt(float (&sr)[8], float (&si)[8], float c, float s, int lane) {
    const bool ctrl = (lane >> CB) & 1;
    const float ce = ctrl ? c : 1.f;
    const float se = ctrl ? s : 0.f;
#pragma unroll
    for (int k = 0; k < 8; ++k) {
        if ((k >> TB) & 1) continue;
        const int k1 = k | (1 << TB);
        float a0r = sr[k], a0i = si[k], a1r = sr[k1], a1i = si[k1];
        sr[k]  = ce * a0r + se * a1i;
        si[k]  = ce * a0i - se * a1r;
        sr[k1] = ce * a1r + se * a0i;
        si[k1] = ce * a1i - se * a0r;
    }
}

template<int CB, int TB>
__device__ __forceinline__ void crx_tt(float (&sr)[8], float (&si)[8], float c, float s) {
#pragma unroll
    for (int k = 0; k < 8; ++k) {
        if (!((k >> CB) & 1)) continue;
        if ((k >> TB) & 1) continue;
        const int k1 = k | (1 << TB);
        float a0r = sr[k], a0i = si[k], a1r = sr[k1], a1i = si[k1];
        sr[k]  = c * a0r + s * a1i;
        si[k]  = c * a0i - s * a1r;
        sr[k1] = c * a1r + s * a0i;
        si[k1] = c * a1i - s * a0r;
    }
}

template<int CB, int TB>
__device__ __forceinline__ void crx_tl(float (&sr)[8], float (&si)[8], float c, float s) {
#pragma unroll
    for (int k = 0; k < 8; ++k) {
        if (!((k >> CB) & 1)) continue;
        float pr = shx(sr[k], 1 << TB);
        float pi = shx(si[k], 1 << TB);
        sr[k] = c * sr[k] + s * pi;
        si[k] = c * si[k] - s * pr;
    }
}

__global__ __launch_bounds__(256) void qmlp_kernel(
    const float* __restrict__ x, const float* __restrict__ rot_w,
    const float* __restrict__ crx_w, const float* __restrict__ fc_w,
    const float* __restrict__ fc_b, float* __restrict__ out, int B)
{
    __shared__ float rotm[NL * NQ * 8];
    __shared__ float crxm[NL * NQ * 2];
    __shared__ float fcw[NC * NQ];
    __shared__ float fcbs[NC];

    const int tid = threadIdx.x;
    if (tid < NL * NQ) {
        const float phi = rot_w[tid * 3 + 0];
        const float th  = rot_w[tid * 3 + 1];
        const float om  = rot_w[tid * 3 + 2];
        float st, ct; sincosf(0.5f * th, &st, &ct);
        float spo, cpo; sincosf(0.5f * (phi + om), &spo, &cpo);
        float smo, cmo; sincosf(0.5f * (phi - om), &smo, &cmo);
        float* m = rotm + tid * 8;
        m[0] =  ct * cpo; m[1] = -ct * spo;   // m00 = e^{-i(phi+om)/2} ct
        m[2] = -st * cmo; m[3] = -st * smo;   // m01 = -e^{+i(phi-om)/2} st
        m[4] =  st * cmo; m[5] = -st * smo;   // m10 =  e^{-i(phi-om)/2} st
        m[6] =  ct * cpo; m[7] =  ct * spo;   // m11 = e^{+i(phi+om)/2} ct
        float sc, cc; sincosf(0.5f * crx_w[tid], &sc, &cc);
        crxm[tid * 2 + 0] = cc; crxm[tid * 2 + 1] = sc;
    }
    if (tid < NC * NQ) fcw[tid] = fc_w[tid];
    if (tid < NC) fcbs[tid] = fc_b[tid];
    __syncthreads();

    const int lane = tid & 63;
    const int b = blockIdx.x * 4 + (tid >> 6);
    if (b >= B) return;

    // per-sample RX half-angle cos/sin (same x re-embedded every layer)
    float cx[NQ], sx[NQ];
#pragma unroll
    for (int w = 0; w < NQ; ++w) sincosf(0.5f * x[b * NQ + w], &sx[w], &cx[w]);

    // state: lane owns amplitudes idx = lane*8 + k. bit(wire w) = 8-w;
    // wires 0..5 -> lane bits 5..0, wires 6..8 -> local bits 2..0.
    float sr[8], si[8];

    // ---- Layer 0 single-qubit block applied to |0..0>: direct product state ----
    {
        const float* M = rotm;  // layer 0 Rot matrices
        float ar = 1.f, ai = 0.f;
#pragma unroll
        for (int w = 0; w < 6; ++w) {
            const float* m = M + w * 8;
            float c = cx[w], s = sx[w];
            int bit = (lane >> (5 - w)) & 1;
            // column 0 of U = Rot*RX: (U00, U10)
            float u0r = m[0]*c + s*m[3], u0i = m[1]*c - s*m[2];
            float u1r = m[4]*c + s*m[7], u1i = m[5]*c - s*m[6];
            float vr = bit ? u1r : u0r;
            float vi = bit ? u1i : u0i;
            float nr = ar * vr - ai * vi;
            float ni = ar * vi + ai * vr;
            ar = nr; ai = ni;
        }
        float vr[3][2], vi[3][2];
#pragma unroll
        for (int j = 0; j < 3; ++j) {
            const float* m = M + (6 + j) * 8;
            float c = cx[6 + j], s = sx[6 + j];
            vr[j][0] = m[0]*c + s*m[3]; vi[j][0] = m[1]*c - s*m[2];
            vr[j][1] = m[4]*c + s*m[7]; vi[j][1] = m[5]*c - s*m[6];
        }
        float t6r[2], t6i[2];
#pragma unroll
        for (int bb = 0; bb < 2; ++bb) {
            t6r[bb] = ar * vr[0][bb] - ai * vi[0][bb];
            t6i[bb] = ar * vi[0][bb] + ai * vr[0][bb];
        }
        float t67r[4], t67i[4];
#pragma unroll
        for (int k = 0; k < 4; ++k) {
            int b6 = k >> 1, b7 = k & 1;
            t67r[k] = t6r[b6] * vr[1][b7] - t6i[b6] * vi[1][b7];
            t67i[k] = t6r[b6] * vi[1][b7] + t6i[b6] * vr[1][b7];
        }
#pragma unroll
        for (int k = 0; k < 8; ++k) {
            int b67 = k >> 1, b8 = k & 1;
            sr[k] = t67r[b67] * vr[2][b8] - t67i[b67] * vi[2][b8];
            si[k] = t67r[b67] * vi[2][b8] + t67i[b67] * vr[2][b8];
        }
    }

    // ---- Layer 0 CRX ring + layers 1..4 ----
    for (int n = 0; n < NL; ++n) {
        if (n > 0) {
            const float* M = rotm + n * NQ * 8;
            fused_cross<5>(sr, si, M + 0 * 8, cx[0], sx[0], lane);
            fused_cross<4>(sr, si, M + 1 * 8, cx[1], sx[1], lane);
            fused_cross<3>(sr, si, M + 2 * 8, cx[2], sx[2], lane);
            fused_cross<2>(sr, si, M + 3 * 8, cx[3], sx[3], lane);
            fused_cross<1>(sr, si, M + 4 * 8, cx[4], sx[4], lane);
            fused_cross<0>(sr, si, M + 5 * 8, cx[5], sx[5], lane);
            fused_local<2>(sr, si, M + 6 * 8, cx[6], sx[6]);
            fused_local<1>(sr, si, M + 7 * 8, cx[7], sx[7]);
            fused_local<0>(sr, si, M + 8 * 8, cx[8], sx[8]);
        }
        const float* C = crxm + n * NQ * 2;
        crx_ll<5, 4>(sr, si, C[0],  C[1],  lane);  // w=0
        crx_ll<4, 3>(sr, si, C[2],  C[3],  lane);  // w=1
        crx_ll<3, 2>(sr, si, C[4],  C[5],  lane);  // w=2
        crx_ll<2, 1>(sr, si, C[6],  C[7],  lane);  // w=3
        crx_ll<1, 0>(sr, si, C[8],  C[9],  lane);  // w=4
        crx_lt<0, 2>(sr, si, C[10], C[11], lane);  // w=5
        crx_tt<2, 1>(sr, si, C[12], C[13]);        // w=6
        crx_tt<1, 0>(sr, si, C[14], C[15]);        // w=7
        crx_tl<0, 5>(sr, si, C[16], C[17]);        // w=8
    }

    // ---- probabilities and <Z_w> ----
    float p[8];
#pragma unroll
    for (int k = 0; k < 8; ++k) p[k] = sr[k] * sr[k] + si[k] * si[k];
    float psum = 0.f;
#pragma unroll
    for (int k = 0; k < 8; ++k) psum += p[k];

    // lane-bit <Z>'s via shared-prefix signed reduction: 21 shfl total
    float t = psum;
    float d[6];
#pragma unroll
    for (int bb = 0; bb < 6; ++bb) {
#pragma unroll
        for (int j = 0; j < 6; ++j) {
            if (j < bb) d[j] += shx(d[j], 1 << bb);
        }
        float o = shx(t, 1 << bb);
        d[bb] = ((lane >> bb) & 1) ? (o - t) : (t - o);
        t += o;
    }
    // local-bit <Z>'s: plain 6-step butterflies
    float e6 = (p[0] + p[1] + p[2] + p[3]) - (p[4] + p[5] + p[6] + p[7]);
    float e7 = (p[0] + p[1] + p[4] + p[5]) - (p[2] + p[3] + p[6] + p[7]);
    float e8 = (p[0] + p[2] + p[4] + p[6]) - (p[1] + p[3] + p[5] + p[7]);
#pragma unroll
    for (int m = 1; m < 64; m <<= 1) {
        e6 += shx(e6, m); e7 += shx(e7, m); e8 += shx(e8, m);
    }

    float ev[NQ];
#pragma unroll
    for (int w = 0; w < 6; ++w) ev[w] = d[5 - w];
    ev[6] = e6; ev[7] = e7; ev[8] = e8;

    // ---- linear head + log_softmax: lane c (<10) owns class c ----
    float lval = -INFINITY;
    if (lane < NC) {
        float dd = fcbs[lane];
        const float* fw = fcw + lane * NQ;
#pragma unroll
        for (int w = 0; w < NQ; ++w) dd += ev[w] * fw[w];
        lval = dd;
    }
    float mx = lval;
    mx = fmaxf(mx, shx(mx, 1));
    mx = fmaxf(mx, shx(mx, 2));
    mx = fmaxf(mx, shx(mx, 4));
    mx = fmaxf(mx, shx(mx, 8));
    float e = (lane < NC) ? expf(lval - mx) : 0.f;
    float se = e;
    se += shx(se, 1); se += shx(se, 2); se += shx(se, 4); se += shx(se, 8);
    if (lane < NC) out[b * NC + lane] = lval - mx - logf(se);
}

extern "C" void kernel_launch(void* const* d_in, const int* in_sizes, int n_in,
                              void* d_out, int out_size, void* d_ws, size_t ws_size,
                              hipStream_t stream) {
    const float* x     = (const float*)d_in[0];
    const float* rot_w = (const float*)d_in[1];
    const float* crx_w = (const float*)d_in[2];
    const float* fc_w  = (const float*)d_in[3];
    const float* fc_b  = (const float*)d_in[4];
    float* out = (float*)d_out;
    const int B = in_sizes[0] / NQ;          // 4096
    const int blocks = (B + 3) / 4;          // 4 samples (waves) per 256-thread block
    qmlp_kernel<<<blocks, 256, 0, stream>>>(x, rot_w, crx_w, fc_w, fc_b, out, B);
}

// Round 3
// 54.749 us; speedup vs baseline: 1.5296x; 1.1936x over previous
//
#include <hip/hip_runtime.h>
#include <math.h>

#define NQ 9
#define NL 5
#define NC 10

// XOR-lane exchange. mask is always a compile-time constant after inlining;
// dead branches fold, and the DPP/swizzle builtins get literal control args.
//  m=1,2  : quad_perm DPP            (VALU)
//  m=4    : bank-masked row_shl/shr  (VALU, 2 ops)
//  m=8    : row_ror:8  ((i+8)%16 == i^8 within a 16-lane row)  (VALU)
//  m=16   : ds_swizzle xor16 (stays within 32-lane group)      (LDS, no addr)
//  m=32   : ds_bpermute via __shfl_xor (only exchange crossing 32-lane halves)
__device__ __forceinline__ float xmove(float x, int mask) {
    if (mask == 1)
        return __int_as_float(__builtin_amdgcn_update_dpp(0, __float_as_int(x), 0xB1, 0xF, 0xF, true));
    if (mask == 2)
        return __int_as_float(__builtin_amdgcn_update_dpp(0, __float_as_int(x), 0x4E, 0xF, 0xF, true));
    if (mask == 4) {
        int t = __builtin_amdgcn_update_dpp(0, __float_as_int(x), 0x104, 0xF, 0x5, false); // row_shl:4, banks 0,2
        t = __builtin_amdgcn_update_dpp(t, __float_as_int(x), 0x114, 0xF, 0xA, false);     // row_shr:4, banks 1,3
        return __int_as_float(t);
    }
    if (mask == 8)
        return __int_as_float(__builtin_amdgcn_update_dpp(0, __float_as_int(x), 0x128, 0xF, 0xF, true));
    if (mask == 16)
        return __int_as_float(__builtin_amdgcn_ds_swizzle(__float_as_int(x), 0x401F));
    return __shfl_xor(x, 32, 64);
}

// ---- fused (Rot*RX) general 2x2 on a lane bit ----
template<int LB>
__device__ __forceinline__ void fused_cross(float (&sr)[8], float (&si)[8],
                                            const float* __restrict__ m,
                                            float c, float s, int lane) {
    const int bit = (lane >> LB) & 1;
    float mAr = bit ? m[6] : m[0];
    float mAi = bit ? m[7] : m[1];
    float mBr = bit ? m[4] : m[2];
    float mBi = bit ? m[5] : m[3];
    float dr = mAr * c + s * mBi;
    float di = mAi * c - s * mBr;
    float er = mBr * c + s * mAi;
    float ei = mBi * c - s * mAr;
#pragma unroll
    for (int k = 0; k < 8; ++k) {
        float pr = xmove(sr[k], 1 << LB);
        float pi = xmove(si[k], 1 << LB);
        float ar = sr[k], ai = si[k];
        sr[k] = dr * ar - di * ai + er * pr - ei * pi;
        si[k] = dr * ai + di * ar + er * pi + ei * pr;
    }
}

// ---- fused (Rot*RX) general 2x2 on a local bit ----
template<int B>
__device__ __forceinline__ void fused_local(float (&sr)[8], float (&si)[8],
                                            const float* __restrict__ m,
                                            float c, float s) {
    float u00r = m[0]*c + s*m[3], u00i = m[1]*c - s*m[2];
    float u01r = m[2]*c + s*m[1], u01i = m[3]*c - s*m[0];
    float u10r = m[4]*c + s*m[7], u10i = m[5]*c - s*m[6];
    float u11r = m[6]*c + s*m[5], u11i = m[7]*c - s*m[4];
#pragma unroll
    for (int k = 0; k < 8; ++k) {
        if ((k >> B) & 1) continue;
        const int k1 = k | (1 << B);
        float a0r = sr[k], a0i = si[k], a1r = sr[k1], a1i = si[k1];
        sr[k]  = u00r*a0r - u00i*a0i + u01r*a1r - u01i*a1i;
        si[k]  = u00r*a0i + u00i*a0r + u01r*a1i + u01i*a1r;
        sr[k1] = u10r*a0r - u10i*a0i + u11r*a1r - u11i*a1i;
        si[k1] = u10r*a0i + u10i*a0r + u11r*a1i + u11i*a1r;
    }
}

// ---- CRX variants ----
template<int CB, int TB>
__device__ __forceinline__ void crx_ll(float (&sr)[8], float (&si)[8], float c, float s, int lane) {
    const bool ctrl = (lane >> CB) & 1;
    const float ce = ctrl ? c : 1.f;
    const float se = ctrl ? s : 0.f;
#pragma unroll
    for (int k = 0; k < 8; ++k) {
        float pr = xmove(sr[k], 1 << TB);
        float pi = xmove(si[k], 1 << TB);
        sr[k] = ce * sr[k] + se * pi;
        si[k] = ce * si[k] - se * pr;
    }
}

template<int CB, int TB>
__device__ __forceinline__ void crx_lt(float (&sr)[8], float (&si)[8], float c, float s, int lane) {
    const bool ctrl = (lane >> CB) & 1;
    const float ce = ctrl ? c : 1.f;
    const float se = ctrl ? s : 0.f;
#pragma unroll
    for (int k = 0; k < 8; ++k) {
        if ((k >> TB) & 1) continue;
        const int k1 = k | (1 << TB);
        float a0r = sr[k], a0i = si[k], a1r = sr[k1], a1i = si[k1];
        sr[k]  = ce * a0r + se * a1i;
        si[k]  = ce * a0i - se * a1r;
        sr[k1] = ce * a1r + se * a0i;
        si[k1] = ce * a1i - se * a0r;
    }
}

template<int CB, int TB>
__device__ __forceinline__ void crx_tt(float (&sr)[8], float (&si)[8], float c, float s) {
#pragma unroll
    for (int k = 0; k < 8; ++k) {
        if (!((k >> CB) & 1)) continue;
        if ((k >> TB) & 1) continue;
        const int k1 = k | (1 << TB);
        float a0r = sr[k], a0i = si[k], a1r = sr[k1], a1i = si[k1];
        sr[k]  = c * a0r + s * a1i;
        si[k]  = c * a0i - s * a1r;
        sr[k1] = c * a1r + s * a0i;
        si[k1] = c * a1i - s * a0r;
    }
}

template<int CB, int TB>
__device__ __forceinline__ void crx_tl(float (&sr)[8], float (&si)[8], float c, float s) {
#pragma unroll
    for (int k = 0; k < 8; ++k) {
        if (!((k >> CB) & 1)) continue;
        float pr = xmove(sr[k], 1 << TB);
        float pi = xmove(si[k], 1 << TB);
        sr[k] = c * sr[k] + s * pi;
        si[k] = c * si[k] - s * pr;
    }
}

__global__ __launch_bounds__(256) void qmlp_kernel(
    const float* __restrict__ x, const float* __restrict__ rot_w,
    const float* __restrict__ crx_w, const float* __restrict__ fc_w,
    const float* __restrict__ fc_b, float* __restrict__ out, int B)
{
    __shared__ float rotm[NL * NQ * 8];
    __shared__ float crxm[NL * NQ * 2];
    __shared__ float fcw[NC * NQ];
    __shared__ float fcbs[NC];

    const int tid = threadIdx.x;
    if (tid < NL * NQ) {
        const float phi = rot_w[tid * 3 + 0];
        const float th  = rot_w[tid * 3 + 1];
        const float om  = rot_w[tid * 3 + 2];
        float st, ct; sincosf(0.5f * th, &st, &ct);
        float spo, cpo; sincosf(0.5f * (phi + om), &spo, &cpo);
        float smo, cmo; sincosf(0.5f * (phi - om), &smo, &cmo);
        float* m = rotm + tid * 8;
        m[0] =  ct * cpo; m[1] = -ct * spo;
        m[2] = -st * cmo; m[3] = -st * smo;
        m[4] =  st * cmo; m[5] = -st * smo;
        m[6] =  ct * cpo; m[7] =  ct * spo;
        float sc, cc; sincosf(0.5f * crx_w[tid], &sc, &cc);
        crxm[tid * 2 + 0] = cc; crxm[tid * 2 + 1] = sc;
    }
    if (tid < NC * NQ) fcw[tid] = fc_w[tid];
    if (tid < NC) fcbs[tid] = fc_b[tid];
    __syncthreads();

    const int lane = tid & 63;
    const int b = blockIdx.x * 4 + (tid >> 6);
    if (b >= B) return;

    // per-sample RX half-angle cos/sin (fast hw sin/cos: |err|~1e-6 << 6.6e-2 tol)
    float cx[NQ], sx[NQ];
#pragma unroll
    for (int w = 0; w < NQ; ++w) __sincosf(0.5f * x[b * NQ + w], &sx[w], &cx[w]);

    // lane owns amplitudes idx = lane*8 + k; wire w -> bit 8-w:
    // wires 0..5 -> lane bits 5..0, wires 6..8 -> local bits 2..0.
    float sr[8], si[8];

    // ---- Layer 0 single-qubit block on |0..0>: direct product state ----
    {
        const float* M = rotm;
        float ar = 1.f, ai = 0.f;
#pragma unroll
        for (int w = 0; w < 6; ++w) {
            const float* m = M + w * 8;
            float c = cx[w], s = sx[w];
            int bit = (lane >> (5 - w)) & 1;
            float u0r = m[0]*c + s*m[3], u0i = m[1]*c - s*m[2];
            float u1r = m[4]*c + s*m[7], u1i = m[5]*c - s*m[6];
            float vr = bit ? u1r : u0r;
            float vi = bit ? u1i : u0i;
            float nr = ar * vr - ai * vi;
            float ni = ar * vi + ai * vr;
            ar = nr; ai = ni;
        }
        float vr[3][2], vi[3][2];
#pragma unroll
        for (int j = 0; j < 3; ++j) {
            const float* m = M + (6 + j) * 8;
            float c = cx[6 + j], s = sx[6 + j];
            vr[j][0] = m[0]*c + s*m[3]; vi[j][0] = m[1]*c - s*m[2];
            vr[j][1] = m[4]*c + s*m[7]; vi[j][1] = m[5]*c - s*m[6];
        }
        float t6r[2], t6i[2];
#pragma unroll
        for (int bb = 0; bb < 2; ++bb) {
            t6r[bb] = ar * vr[0][bb] - ai * vi[0][bb];
            t6i[bb] = ar * vi[0][bb] + ai * vr[0][bb];
        }
        float t67r[4], t67i[4];
#pragma unroll
        for (int k = 0; k < 4; ++k) {
            int b6 = k >> 1, b7 = k & 1;
            t67r[k] = t6r[b6] * vr[1][b7] - t6i[b6] * vi[1][b7];
            t67i[k] = t6r[b6] * vi[1][b7] + t6i[b6] * vr[1][b7];
        }
#pragma unroll
        for (int k = 0; k < 8; ++k) {
            int b67 = k >> 1, b8 = k & 1;
            sr[k] = t67r[b67] * vr[2][b8] - t67i[b67] * vi[2][b8];
            si[k] = t67r[b67] * vi[2][b8] + t67i[b67] * vr[2][b8];
        }
    }

    // ---- Layer 0 CRX ring + layers 1..4 ----
    for (int n = 0; n < NL; ++n) {
        if (n > 0) {
            const float* M = rotm + n * NQ * 8;
            fused_cross<5>(sr, si, M + 0 * 8, cx[0], sx[0], lane);
            fused_cross<4>(sr, si, M + 1 * 8, cx[1], sx[1], lane);
            fused_cross<3>(sr, si, M + 2 * 8, cx[2], sx[2], lane);
            fused_cross<2>(sr, si, M + 3 * 8, cx[3], sx[3], lane);
            fused_cross<1>(sr, si, M + 4 * 8, cx[4], sx[4], lane);
            fused_cross<0>(sr, si, M + 5 * 8, cx[5], sx[5], lane);
            fused_local<2>(sr, si, M + 6 * 8, cx[6], sx[6]);
            fused_local<1>(sr, si, M + 7 * 8, cx[7], sx[7]);
            fused_local<0>(sr, si, M + 8 * 8, cx[8], sx[8]);
        }
        const float* C = crxm + n * NQ * 2;
        crx_ll<5, 4>(sr, si, C[0],  C[1],  lane);  // w=0
        crx_ll<4, 3>(sr, si, C[2],  C[3],  lane);  // w=1
        crx_ll<3, 2>(sr, si, C[4],  C[5],  lane);  // w=2
        crx_ll<2, 1>(sr, si, C[6],  C[7],  lane);  // w=3
        crx_ll<1, 0>(sr, si, C[8],  C[9],  lane);  // w=4
        crx_lt<0, 2>(sr, si, C[10], C[11], lane);  // w=5
        crx_tt<2, 1>(sr, si, C[12], C[13]);        // w=6
        crx_tt<1, 0>(sr, si, C[14], C[15]);        // w=7
        crx_tl<0, 5>(sr, si, C[16], C[17]);        // w=8
    }

    // ---- probabilities and <Z_w> ----
    float p[8];
#pragma unroll
    for (int k = 0; k < 8; ++k) p[k] = sr[k] * sr[k] + si[k] * si[k];
    float psum = 0.f;
#pragma unroll
    for (int k = 0; k < 8; ++k) psum += p[k];

    // lane-bit <Z>'s via shared-prefix signed reduction
    float t = psum;
    float d[6];
#pragma unroll
    for (int bb = 0; bb < 6; ++bb) {
#pragma unroll
        for (int j = 0; j < 6; ++j) {
            if (j < bb) d[j] += xmove(d[j], 1 << bb);
        }
        float o = xmove(t, 1 << bb);
        d[bb] = ((lane >> bb) & 1) ? (o - t) : (t - o);
        t += o;
    }
    // local-bit <Z>'s
    float e6 = (p[0] + p[1] + p[2] + p[3]) - (p[4] + p[5] + p[6] + p[7]);
    float e7 = (p[0] + p[1] + p[4] + p[5]) - (p[2] + p[3] + p[6] + p[7]);
    float e8 = (p[0] + p[2] + p[4] + p[6]) - (p[1] + p[3] + p[5] + p[7]);
#pragma unroll
    for (int m = 1; m < 64; m <<= 1) {
        e6 += xmove(e6, m); e7 += xmove(e7, m); e8 += xmove(e8, m);
    }

    float ev[NQ];
#pragma unroll
    for (int w = 0; w < 6; ++w) ev[w] = d[5 - w];
    ev[6] = e6; ev[7] = e7; ev[8] = e8;

    // ---- linear head + log_softmax: lane c (<10) owns class c ----
    float lval = -INFINITY;
    if (lane < NC) {
        float dd = fcbs[lane];
        const float* fw = fcw + lane * NQ;
#pragma unroll
        for (int w = 0; w < NQ; ++w) dd += ev[w] * fw[w];
        lval = dd;
    }
    float mx = lval;
    mx = fmaxf(mx, xmove(mx, 1));
    mx = fmaxf(mx, xmove(mx, 2));
    mx = fmaxf(mx, xmove(mx, 4));
    mx = fmaxf(mx, xmove(mx, 8));
    float e = (lane < NC) ? expf(lval - mx) : 0.f;
    float se = e;
    se += xmove(se, 1); se += xmove(se, 2); se += xmove(se, 4); se += xmove(se, 8);
    if (lane < NC) out[b * NC + lane] = lval - mx - logf(se);
}

extern "C" void kernel_launch(void* const* d_in, const int* in_sizes, int n_in,
                              void* d_out, int out_size, void* d_ws, size_t ws_size,
                              hipStream_t stream) {
    const float* x     = (const float*)d_in[0];
    const float* rot_w = (const float*)d_in[1];
    const float* crx_w = (const float*)d_in[2];
    const float* fc_w  = (const float*)d_in[3];
    const float* fc_b  = (const float*)d_in[4];
    float* out = (float*)d_out;
    const int B = in_sizes[0] / NQ;
    const int blocks = (B + 3) / 4;
    qmlp_kernel<<<blocks, 256, 0, stream>>>(x, rot_w, crx_w, fc_w, fc_b, out, B);
}

// Round 4
// 37.205 us; speedup vs baseline: 2.2509x; 1.4716x over previous
//
#include <hip/hip_runtime.h>
#include <math.h>

#define NQ 9
#define NL 5
#define NC 10

typedef float v2f __attribute__((ext_vector_type(2)));

__device__ __forceinline__ v2f sp(float x) { v2f r; r.x = x; r.y = x; return r; }

// XOR-lane exchange of a 32-bit value; mask is compile-time constant.
//  m=1,2 : quad_perm DPP; m=4 : bank-masked row_shl/shr (2 DPP); m=8 : row_ror:8
//  m=16  : ds_swizzle xor16; m=32 : ds_bpermute (__shfl_xor)
__device__ __forceinline__ float xmove(float x, int mask) {
    if (mask == 1)
        return __int_as_float(__builtin_amdgcn_update_dpp(0, __float_as_int(x), 0xB1, 0xF, 0xF, true));
    if (mask == 2)
        return __int_as_float(__builtin_amdgcn_update_dpp(0, __float_as_int(x), 0x4E, 0xF, 0xF, true));
    if (mask == 4) {
        int t = __builtin_amdgcn_update_dpp(0, __float_as_int(x), 0x104, 0xF, 0x5, false);
        t = __builtin_amdgcn_update_dpp(t, __float_as_int(x), 0x114, 0xF, 0xA, false);
        return __int_as_float(t);
    }
    if (mask == 8)
        return __int_as_float(__builtin_amdgcn_update_dpp(0, __float_as_int(x), 0x128, 0xF, 0xF, true));
    if (mask == 16)
        return __int_as_float(__builtin_amdgcn_ds_swizzle(__float_as_int(x), 0x401F));
    return __shfl_xor(x, 32, 64);
}

__device__ __forceinline__ v2f xmv2(v2f v, int mask) {
    v2f r; r.x = xmove(v.x, mask); r.y = xmove(v.y, mask); return r;
}

// State packing: lane owns amplitudes k = 0..7; k = (j<<1)|comp.
// wire w -> bit 8-w. wires 0..5 -> lane bits 5..0; wire6 -> j bit1;
// wire7 -> j bit0; wire8 -> float2 component.

// ---- fused (Rot*RX) on a lane bit ----
template<int LB>
__device__ __forceinline__ void fused_cross(v2f (&xr)[4], v2f (&xi)[4],
                                            const float* __restrict__ m,
                                            float c, float s, int lane) {
    const int bit = (lane >> LB) & 1;
    float mAr = bit ? m[6] : m[0];
    float mAi = bit ? m[7] : m[1];
    float mBr = bit ? m[4] : m[2];
    float mBi = bit ? m[5] : m[3];
    float dr = mAr * c + s * mBi;
    float di = mAi * c - s * mBr;
    float er = mBr * c + s * mAi;
    float ei = mBi * c - s * mAr;
#pragma unroll
    for (int j = 0; j < 4; ++j) {
        v2f pr = xmv2(xr[j], 1 << LB);
        v2f pi = xmv2(xi[j], 1 << LB);
        v2f ar = xr[j], ai = xi[j];
        xr[j] = sp(dr)*ar - sp(di)*ai + sp(er)*pr - sp(ei)*pi;
        xi[j] = sp(dr)*ai + sp(di)*ar + sp(er)*pi + sp(ei)*pr;
    }
}

// ---- fused (Rot*RX) on a j bit (wires 6,7) ----
template<int JB>
__device__ __forceinline__ void fused_local_j(v2f (&xr)[4], v2f (&xi)[4],
                                              const float* __restrict__ m,
                                              float c, float s) {
    float u00r = m[0]*c + s*m[3], u00i = m[1]*c - s*m[2];
    float u01r = m[2]*c + s*m[1], u01i = m[3]*c - s*m[0];
    float u10r = m[4]*c + s*m[7], u10i = m[5]*c - s*m[6];
    float u11r = m[6]*c + s*m[5], u11i = m[7]*c - s*m[4];
#pragma unroll
    for (int j = 0; j < 4; ++j) {
        if ((j >> JB) & 1) continue;
        const int j1 = j | (1 << JB);
        v2f a0r = xr[j], a0i = xi[j], a1r = xr[j1], a1i = xi[j1];
        xr[j]  = sp(u00r)*a0r - sp(u00i)*a0i + sp(u01r)*a1r - sp(u01i)*a1i;
        xi[j]  = sp(u00r)*a0i + sp(u00i)*a0r + sp(u01r)*a1i + sp(u01i)*a1r;
        xr[j1] = sp(u10r)*a0r - sp(u10i)*a0i + sp(u11r)*a1r - sp(u11i)*a1i;
        xi[j1] = sp(u10r)*a0i + sp(u10i)*a0r + sp(u11r)*a1i + sp(u11i)*a1r;
    }
}

// ---- fused (Rot*RX) on the component bit (wire 8): broadcast form ----
__device__ __forceinline__ void fused_local_c(v2f (&xr)[4], v2f (&xi)[4],
                                              const float* __restrict__ m,
                                              float c, float s) {
    v2f U0r = { m[0]*c + s*m[3], m[4]*c + s*m[7] };   // {u00r, u10r}
    v2f U0i = { m[1]*c - s*m[2], m[5]*c - s*m[6] };
    v2f U1r = { m[2]*c + s*m[1], m[6]*c + s*m[5] };   // {u01r, u11r}
    v2f U1i = { m[3]*c - s*m[0], m[7]*c - s*m[4] };
#pragma unroll
    for (int j = 0; j < 4; ++j) {
        v2f A0r = xr[j].xx, A0i = xi[j].xx, A1r = xr[j].yy, A1i = xi[j].yy;
        xr[j] = U0r*A0r - U0i*A0i + U1r*A1r - U1i*A1i;
        xi[j] = U0r*A0i + U0i*A0r + U1r*A1i + U1i*A1r;
    }
}

// ---- CRX w=0..4: ctrl lane bit CB, tgt lane bit TB ----
template<int CB, int TB>
__device__ __forceinline__ void crx_ll(v2f (&xr)[4], v2f (&xi)[4], float c, float s, int lane) {
    const bool ctrl = (lane >> CB) & 1;
    const float ce = ctrl ? c : 1.f;
    const float se = ctrl ? s : 0.f;
#pragma unroll
    for (int j = 0; j < 4; ++j) {
        v2f pr = xmv2(xr[j], 1 << TB);
        v2f pi = xmv2(xi[j], 1 << TB);
        xr[j] = sp(ce)*xr[j] + sp(se)*pi;
        xi[j] = sp(ce)*xi[j] - sp(se)*pr;
    }
}

// ---- CRX w=5: ctrl lane bit0 (wire5), tgt j bit1 (wire6) ----
__device__ __forceinline__ void crx_l_j1(v2f (&xr)[4], v2f (&xi)[4], float c, float s, int lane) {
    const bool ctrl = lane & 1;
    const float ce = ctrl ? c : 1.f;
    const float se = ctrl ? s : 0.f;
#pragma unroll
    for (int j = 0; j < 2; ++j) {
        const int j1 = j | 2;
        v2f a0r = xr[j], a0i = xi[j], a1r = xr[j1], a1i = xi[j1];
        xr[j]  = sp(ce)*a0r + sp(se)*a1i;
        xi[j]  = sp(ce)*a0i - sp(se)*a1r;
        xr[j1] = sp(ce)*a1r + sp(se)*a0i;
        xi[j1] = sp(ce)*a1i - sp(se)*a0r;
    }
}

// ---- CRX w=6: ctrl j bit1 (wire6), tgt j bit0 (wire7): pair (2,3) ----
__device__ __forceinline__ void crx_j1_j0(v2f (&xr)[4], v2f (&xi)[4], float c, float s) {
    v2f a0r = xr[2], a0i = xi[2], a1r = xr[3], a1i = xi[3];
    xr[2] = sp(c)*a0r + sp(s)*a1i;
    xi[2] = sp(c)*a0i - sp(s)*a1r;
    xr[3] = sp(c)*a1r + sp(s)*a0i;
    xi[3] = sp(c)*a1i - sp(s)*a0r;
}

// ---- CRX w=7: ctrl j bit0 (wire7, j in {1,3}), tgt component (wire8) ----
__device__ __forceinline__ void crx_j0_c(v2f (&xr)[4], v2f (&xi)[4], float c, float s) {
#pragma unroll
    for (int j = 1; j < 4; j += 2) {
        v2f vr = xr[j], vi = xi[j];
        xr[j] = sp(c)*vr + sp(s)*vi.yx;
        xi[j] = sp(c)*vi - sp(s)*vr.yx;
    }
}

// ---- CRX w=8: ctrl component (wire8), tgt lane bit5 (wire0) ----
__device__ __forceinline__ void crx_c_l5(v2f (&xr)[4], v2f (&xi)[4], float c, float s) {
    const v2f ce = {1.f, c};
    const v2f se = {0.f, s};
#pragma unroll
    for (int j = 0; j < 4; ++j) {
        v2f pr = xmv2(xr[j], 32);
        v2f pi = xmv2(xi[j], 32);
        xr[j] = ce*xr[j] + se*pi;
        xi[j] = ce*xi[j] - se*pr;
    }
}

__global__ __launch_bounds__(256) void qmlp_kernel(
    const float* __restrict__ x, const float* __restrict__ rot_w,
    const float* __restrict__ crx_w, const float* __restrict__ fc_w,
    const float* __restrict__ fc_b, float* __restrict__ out, int B)
{
    __shared__ float rotm[NL * NQ * 8];
    __shared__ float crxm[NL * NQ * 2];
    __shared__ float fcw[NC * NQ];
    __shared__ float fcbs[NC];

    const int tid = threadIdx.x;
    if (tid < NL * NQ) {
        const float phi = rot_w[tid * 3 + 0];
        const float th  = rot_w[tid * 3 + 1];
        const float om  = rot_w[tid * 3 + 2];
        float st, ct; sincosf(0.5f * th, &st, &ct);
        float spo, cpo; sincosf(0.5f * (phi + om), &spo, &cpo);
        float smo, cmo; sincosf(0.5f * (phi - om), &smo, &cmo);
        float* m = rotm + tid * 8;
        m[0] =  ct * cpo; m[1] = -ct * spo;
        m[2] = -st * cmo; m[3] = -st * smo;
        m[4] =  st * cmo; m[5] = -st * smo;
        m[6] =  ct * cpo; m[7] =  ct * spo;
        float sc, cc; sincosf(0.5f * crx_w[tid], &sc, &cc);
        crxm[tid * 2 + 0] = cc; crxm[tid * 2 + 1] = sc;
    }
    if (tid < NC * NQ) fcw[tid] = fc_w[tid];
    if (tid < NC) fcbs[tid] = fc_b[tid];
    __syncthreads();

    const int lane = tid & 63;
    const int b = blockIdx.x * 4 + (tid >> 6);
    if (b >= B) return;

    float cx[NQ], sx[NQ];
#pragma unroll
    for (int w = 0; w < NQ; ++w) __sincosf(0.5f * x[b * NQ + w], &sx[w], &cx[w]);

    v2f xr[4], xi[4];

    // ---- Layer 0 single-qubit block on |0..0>: direct product state ----
    {
        const float* M = rotm;
        float ar = 1.f, ai = 0.f;
#pragma unroll
        for (int w = 0; w < 6; ++w) {
            const float* m = M + w * 8;
            float c = cx[w], s = sx[w];
            int bit = (lane >> (5 - w)) & 1;
            float u0r = m[0]*c + s*m[3], u0i = m[1]*c - s*m[2];
            float u1r = m[4]*c + s*m[7], u1i = m[5]*c - s*m[6];
            float vr = bit ? u1r : u0r;
            float vi = bit ? u1i : u0i;
            float nr = ar * vr - ai * vi;
            float ni = ar * vi + ai * vr;
            ar = nr; ai = ni;
        }
        // wires 6,7 column-0 vectors
        float vr67[2][2], vi67[2][2];
#pragma unroll
        for (int q = 0; q < 2; ++q) {
            const float* m = M + (6 + q) * 8;
            float c = cx[6 + q], s = sx[6 + q];
            vr67[q][0] = m[0]*c + s*m[3]; vi67[q][0] = m[1]*c - s*m[2];
            vr67[q][1] = m[4]*c + s*m[7]; vi67[q][1] = m[5]*c - s*m[6];
        }
        float t6r[2], t6i[2];
#pragma unroll
        for (int bb = 0; bb < 2; ++bb) {
            t6r[bb] = ar * vr67[0][bb] - ai * vi67[0][bb];
            t6i[bb] = ar * vi67[0][bb] + ai * vr67[0][bb];
        }
        float t67r[4], t67i[4];
#pragma unroll
        for (int j = 0; j < 4; ++j) {
            int b6 = j >> 1, b7 = j & 1;
            t67r[j] = t6r[b6] * vr67[1][b7] - t6i[b6] * vi67[1][b7];
            t67i[j] = t6r[b6] * vi67[1][b7] + t6i[b6] * vr67[1][b7];
        }
        // wire 8 column-0, packed over component
        const float* m8 = M + 8 * 8;
        float c8 = cx[8], s8 = sx[8];
        v2f V8r = { m8[0]*c8 + s8*m8[3], m8[4]*c8 + s8*m8[7] };
        v2f V8i = { m8[1]*c8 - s8*m8[2], m8[5]*c8 - s8*m8[6] };
#pragma unroll
        for (int j = 0; j < 4; ++j) {
            xr[j] = sp(t67r[j])*V8r - sp(t67i[j])*V8i;
            xi[j] = sp(t67r[j])*V8i + sp(t67i[j])*V8r;
        }
    }

    // ---- Layer 0 CRX ring + layers 1..4 ----
    for (int n = 0; n < NL; ++n) {
        if (n > 0) {
            const float* M = rotm + n * NQ * 8;
            fused_cross<5>(xr, xi, M + 0 * 8, cx[0], sx[0], lane);
            fused_cross<4>(xr, xi, M + 1 * 8, cx[1], sx[1], lane);
            fused_cross<3>(xr, xi, M + 2 * 8, cx[2], sx[2], lane);
            fused_cross<2>(xr, xi, M + 3 * 8, cx[3], sx[3], lane);
            fused_cross<1>(xr, xi, M + 4 * 8, cx[4], sx[4], lane);
            fused_cross<0>(xr, xi, M + 5 * 8, cx[5], sx[5], lane);
            fused_local_j<1>(xr, xi, M + 6 * 8, cx[6], sx[6]);   // wire6 = j bit1
            fused_local_j<0>(xr, xi, M + 7 * 8, cx[7], sx[7]);   // wire7 = j bit0
            fused_local_c   (xr, xi, M + 8 * 8, cx[8], sx[8]);   // wire8 = component
        }
        const float* C = crxm + n * NQ * 2;
        crx_ll<5, 4>(xr, xi, C[0],  C[1],  lane);  // w=0
        crx_ll<4, 3>(xr, xi, C[2],  C[3],  lane);  // w=1
        crx_ll<3, 2>(xr, xi, C[4],  C[5],  lane);  // w=2
        crx_ll<2, 1>(xr, xi, C[6],  C[7],  lane);  // w=3
        crx_ll<1, 0>(xr, xi, C[8],  C[9],  lane);  // w=4
        crx_l_j1    (xr, xi, C[10], C[11], lane);  // w=5
        crx_j1_j0   (xr, xi, C[12], C[13]);        // w=6
        crx_j0_c    (xr, xi, C[14], C[15]);        // w=7
        crx_c_l5    (xr, xi, C[16], C[17]);        // w=8
    }

    // ---- probabilities and <Z_w> ----
    v2f P[4];
#pragma unroll
    for (int j = 0; j < 4; ++j) P[j] = xr[j]*xr[j] + xi[j]*xi[j];
    float ps[4];
#pragma unroll
    for (int j = 0; j < 4; ++j) ps[j] = P[j].x + P[j].y;
    float psum = ps[0] + ps[1] + ps[2] + ps[3];

    // lane-bit <Z>'s via shared-prefix signed reduction
    float t = psum;
    float d[6];
#pragma unroll
    for (int bb = 0; bb < 6; ++bb) {
#pragma unroll
        for (int jj = 0; jj < 6; ++jj) {
            if (jj < bb) d[jj] += xmove(d[jj], 1 << bb);
        }
        float o = xmove(t, 1 << bb);
        d[bb] = ((lane >> bb) & 1) ? (o - t) : (t - o);
        t += o;
    }
    // local-bit <Z>'s
    float e6 = (ps[0] + ps[1]) - (ps[2] + ps[3]);                   // wire6 = j bit1
    float e7 = (ps[0] + ps[2]) - (ps[1] + ps[3]);                   // wire7 = j bit0
    float e8 = (P[0].x - P[0].y) + (P[1].x - P[1].y)
             + (P[2].x - P[2].y) + (P[3].x - P[3].y);               // wire8 = component
#pragma unroll
    for (int m = 1; m < 64; m <<= 1) {
        e6 += xmove(e6, m); e7 += xmove(e7, m); e8 += xmove(e8, m);
    }

    float ev[NQ];
#pragma unroll
    for (int w = 0; w < 6; ++w) ev[w] = d[5 - w];
    ev[6] = e6; ev[7] = e7; ev[8] = e8;

    // ---- linear head + log_softmax: lane c (<10) owns class c ----
    float lval = -INFINITY;
    if (lane < NC) {
        float dd = fcbs[lane];
        const float* fw = fcw + lane * NQ;
#pragma unroll
        for (int w = 0; w < NQ; ++w) dd += ev[w] * fw[w];
        lval = dd;
    }
    float mx = lval;
    mx = fmaxf(mx, xmove(mx, 1));
    mx = fmaxf(mx, xmove(mx, 2));
    mx = fmaxf(mx, xmove(mx, 4));
    mx = fmaxf(mx, xmove(mx, 8));
    float e = (lane < NC) ? expf(lval - mx) : 0.f;
    float se = e;
    se += xmove(se, 1); se += xmove(se, 2); se += xmove(se, 4); se += xmove(se, 8);
    if (lane < NC) out[b * NC + lane] = lval - mx - logf(se);
}

extern "C" void kernel_launch(void* const* d_in, const int* in_sizes, int n_in,
                              void* d_out, int out_size, void* d_ws, size_t ws_size,
                              hipStream_t stream) {
    const float* x     = (const float*)d_in[0];
    const float* rot_w = (const float*)d_in[1];
    const float* crx_w = (const float*)d_in[2];
    const float* fc_w  = (const float*)d_in[3];
    const float* fc_b  = (const float*)d_in[4];
    float* out = (float*)d_out;
    const int B = in_sizes[0] / NQ;
    const int blocks = (B + 3) / 4;
    qmlp_kernel<<<blocks, 256, 0, stream>>>(x, rot_w, crx_w, fc_w, fc_b, out, B);
}